// Round 13
// baseline (134.035 us; speedup 1.0000x reference)
//
#include <hip/hip_runtime.h>

#define NBATCH 4
#define CIN 256
#define CATT 32
#define NPIX 4096

static constexpr float LOG2E_F = 1.4426950408889634f;

typedef __attribute__((ext_vector_type(8))) short bf16x8;
typedef __attribute__((ext_vector_type(4))) float f32x4;

__device__ __forceinline__ unsigned short f2bf_rne(float f) {
    unsigned u = __builtin_bit_cast(unsigned, f);
    return (unsigned short)((u + 0x7fffu + ((u >> 16) & 1u)) >> 16);
}
__device__ __forceinline__ float bf2f(unsigned short h) {
    unsigned u = (unsigned)h << 16;
    return __builtin_bit_cast(float, u);
}
__device__ __forceinline__ void split8(const float* p, bf16x8& hi, bf16x8& lo) {
    const float4 a = *reinterpret_cast<const float4*>(p);
    const float4 b = *reinterpret_cast<const float4*>(p + 4);
    const float f[8] = {a.x, a.y, a.z, a.w, b.x, b.y, b.z, b.w};
    #pragma unroll
    for (int e = 0; e < 8; ++e) {
        const unsigned short h = f2bf_rne(f[e]);
        hi[e] = (short)h;
        lo[e] = (short)f2bf_rne(f[e] - bf2f(h));
    }
}
__device__ __forceinline__ bf16x8 cvt8(const float* p) {
    const float4 a = *reinterpret_cast<const float4*>(p);
    const float4 b = *reinterpret_cast<const float4*>(p + 4);
    const float f[8] = {a.x, a.y, a.z, a.w, b.x, b.y, b.z, b.w};
    bf16x8 r;
    #pragma unroll
    for (int e = 0; e < 8; ++e) r[e] = (short)f2bf_rne(f[e]);
    return r;
}
// async global -> LDS, 16B per lane (dest = uniform base + lane*16)
__device__ __forceinline__ void gl_lds16(const unsigned short* g, unsigned short* l) {
    __builtin_amdgcn_global_load_lds(
        (const __attribute__((address_space(1))) unsigned int*)g,
        (__attribute__((address_space(3))) unsigned int*)l, 16, 0, 0);
}

// ---------------------------------------------------------------------------
// K0: x[b][c][n] f32 -> xT[b][n][256] bf16  (proven, unchanged)
// ---------------------------------------------------------------------------
__global__ __launch_bounds__(256, 2)
void transpose_kernel(const float* __restrict__ x, unsigned short* __restrict__ xT)
{
    __shared__ unsigned short sT[64][68];
    const int t = threadIdx.x;
    const int nblk = blockIdx.x * 64;
    const int cblk = blockIdx.y * 64;
    const int b = blockIdx.z;
    const float* xb = x + ((size_t)b * CIN + cblk) * NPIX + nblk;
    const int lc = t >> 2, ln = (t & 3) << 4;
    #pragma unroll
    for (int u = 0; u < 4; ++u) {
        const float4 v = *reinterpret_cast<const float4*>(&xb[(size_t)lc * NPIX + ln + 4 * u]);
        sT[ln + 4 * u + 0][lc] = f2bf_rne(v.x);
        sT[ln + 4 * u + 1][lc] = f2bf_rne(v.y);
        sT[ln + 4 * u + 2][lc] = f2bf_rne(v.z);
        sT[ln + 4 * u + 3][lc] = f2bf_rne(v.w);
    }
    __syncthreads();
    const int rn = t >> 2, cs = (t & 3) << 4;
    const uint2 d0 = *reinterpret_cast<const uint2*>(&sT[rn][cs + 0]);
    const uint2 d1 = *reinterpret_cast<const uint2*>(&sT[rn][cs + 4]);
    const uint2 d2 = *reinterpret_cast<const uint2*>(&sT[rn][cs + 8]);
    const uint2 d3 = *reinterpret_cast<const uint2*>(&sT[rn][cs + 12]);
    unsigned short* dst = xT + ((size_t)b * NPIX + nblk + rn) * CIN + cblk + cs;
    *reinterpret_cast<uint4*>(dst)     = make_uint4(d0.x, d0.y, d1.x, d1.y);
    *reinterpret_cast<uint4*>(dst + 8) = make_uint4(d2.x, d2.y, d3.x, d3.y);
}

// ---------------------------------------------------------------------------
// K1 (FUSED): q/k/v projection in one kernel (proven in R12).
//  - v part: proj_v body verbatim (all 4 waves), epilogue without rs.
//  - q/k part: proj_qk body verbatim on waves 0,1 (nq = n0 + 16w).
// grid (NPIX/32, NBATCH), block 256.
// ---------------------------------------------------------------------------
__global__ __launch_bounds__(256, 2)
void proj_fused_kernel(const float* __restrict__ Wq, const float* __restrict__ bq,
                       const float* __restrict__ Wk, const float* __restrict__ bk,
                       const float* __restrict__ Wv, const float* __restrict__ bv,
                       const float* __restrict__ gamma,
                       const unsigned short* __restrict__ xT,
                       unsigned short* __restrict__ qt, unsigned short* __restrict__ kt,
                       unsigned short* __restrict__ vt)
{
    const int t = threadIdx.x, w = t >> 6, l = t & 63, lr = l & 15, lg = l >> 4;
    const int b = blockIdx.y;
    const int n0 = blockIdx.x * 32;

    // ---- q/k part (waves 0,1): proj_qk body verbatim at nq = n0 + 16w
    if (w < 2) {
        const int nq = n0 + 16 * w;
        const unsigned short* xrow = xT + ((size_t)b * NPIX + nq + lr) * CIN + lg * 8;
        f32x4 aq[2] = {{0.f,0.f,0.f,0.f},{0.f,0.f,0.f,0.f}};
        f32x4 ak2[2] = {{0.f,0.f,0.f,0.f},{0.f,0.f,0.f,0.f}};
        #pragma unroll
        for (int ks = 0; ks < 8; ++ks) {
            const int ko = ks * 32 + lg * 8;
            const bf16x8 bx = *reinterpret_cast<const bf16x8*>(xrow + ks * 32);
            #pragma unroll
            for (int mt = 0; mt < 2; ++mt) {
                bf16x8 wh, wl;
                split8(&Wq[(size_t)(mt * 16 + lr) * CIN + ko], wh, wl);
                aq[mt] = __builtin_amdgcn_mfma_f32_16x16x32_bf16(wh, bx, aq[mt], 0, 0, 0);
                aq[mt] = __builtin_amdgcn_mfma_f32_16x16x32_bf16(wl, bx, aq[mt], 0, 0, 0);
                split8(&Wk[(size_t)(mt * 16 + lr) * CIN + ko], wh, wl);
                ak2[mt] = __builtin_amdgcn_mfma_f32_16x16x32_bf16(wh, bx, ak2[mt], 0, 0, 0);
                ak2[mt] = __builtin_amdgcn_mfma_f32_16x16x32_bf16(wl, bx, ak2[mt], 0, 0, 0);
            }
        }
        #pragma unroll
        for (int mt = 0; mt < 2; ++mt) {
            const float4 b4q = *reinterpret_cast<const float4*>(&bq[16 * mt + (lg << 2)]);
            const float4 b4k = *reinterpret_cast<const float4*>(&bk[16 * mt + (lg << 2)]);
            ushort4 uq, uk;
            uq.x = f2bf_rne(LOG2E_F * (aq[mt][0] + b4q.x));
            uq.y = f2bf_rne(LOG2E_F * (aq[mt][1] + b4q.y));
            uq.z = f2bf_rne(LOG2E_F * (aq[mt][2] + b4q.z));
            uq.w = f2bf_rne(LOG2E_F * (aq[mt][3] + b4q.w));
            uk.x = f2bf_rne(ak2[mt][0] + b4k.x);
            uk.y = f2bf_rne(ak2[mt][1] + b4k.y);
            uk.z = f2bf_rne(ak2[mt][2] + b4k.z);
            uk.w = f2bf_rne(ak2[mt][3] + b4k.w);
            const size_t base = ((size_t)b * NPIX + nq + lr) * CATT + 16 * mt + (lg << 2);
            *reinterpret_cast<ushort4*>(&qt[base]) = uq;
            *reinterpret_cast<ushort4*>(&kt[base]) = uk;
        }
    }

    // ---- v part (all waves): proj_v body verbatim, epilogue without rs
    const int cb = 64 * w;
    const unsigned short* xa = xT + ((size_t)b * NPIX + n0) * CIN;
    f32x4 acc[2][4] = {};
    #pragma unroll
    for (int ks = 0; ks < 8; ++ks) {
        const int ko = ks * 32 + lg * 8;
        bf16x8 af[2];
        #pragma unroll
        for (int mt = 0; mt < 2; ++mt)
            af[mt] = *reinterpret_cast<const bf16x8*>(&xa[(size_t)(16 * mt + lr) * CIN + ko]);
        #pragma unroll
        for (int ct = 0; ct < 4; ++ct) {
            const bf16x8 wf = cvt8(&Wv[(size_t)(cb + 16 * ct + lr) * CIN + ko]);
            #pragma unroll
            for (int mt = 0; mt < 2; ++mt)
                acc[mt][ct] = __builtin_amdgcn_mfma_f32_16x16x32_bf16(af[mt], wf, acc[mt][ct], 0, 0, 0);
        }
    }
    const float gv = gamma[0];
    #pragma unroll
    for (int mt = 0; mt < 2; ++mt) {
        const int nr = n0 + 16 * mt + (lg << 2);
        #pragma unroll
        for (int ct = 0; ct < 4; ++ct) {
            const int c = cb + 16 * ct + lr;
            const float bb = bv[c];
            ushort4 u;
            u.x = f2bf_rne(gv * (acc[mt][ct][0] + bb));
            u.y = f2bf_rne(gv * (acc[mt][ct][1] + bb));
            u.z = f2bf_rne(gv * (acc[mt][ct][2] + bb));
            u.w = f2bf_rne(gv * (acc[mt][ct][3] + bb));
            *reinterpret_cast<ushort4*>(&vt[((size_t)b * CIN + c) * NPIX + nr]) = u;
        }
    }
}

// ---------------------------------------------------------------------------
// K2: stats via MFMA, software-pipelined (proven, unchanged)
// ---------------------------------------------------------------------------
__global__ __launch_bounds__(256, 2)
void stats_kernel(const unsigned short* __restrict__ qt,
                  const unsigned short* __restrict__ kt, float* __restrict__ rs)
{
    __shared__ float sred[4][16];
    const int n = blockIdx.x;
    const int b = n & 3;
    const int jblk = (n >> 2) * 32;
    const int t = threadIdx.x, w = t >> 6, l = t & 63, lr = l & 15, lg = l >> 4;
    const int jsl = w & 1;
    const int ih = w >> 1;
    const unsigned short* qb = qt + (size_t)b * NPIX * CATT;
    const unsigned short* kb = kt + (size_t)b * NPIX * CATT;

    const bf16x8 kfrag = *reinterpret_cast<const bf16x8*>(
        &kb[(size_t)(jblk + 16 * jsl + lr) * CATT + lg * 8]);
    const f32x4 zero = {0.f, 0.f, 0.f, 0.f};
    const unsigned short* qp = qb + (size_t)(ih * 2048 + lr) * CATT + lg * 8;

    float s0 = 0.f, s1 = 0.f, s2 = 0.f, s3 = 0.f;
    bf16x8 qc0 = *reinterpret_cast<const bf16x8*>(qp);
    bf16x8 qc1 = *reinterpret_cast<const bf16x8*>(qp + 16 * CATT);
    bf16x8 qc2 = *reinterpret_cast<const bf16x8*>(qp + 32 * CATT);
    bf16x8 qc3 = *reinterpret_cast<const bf16x8*>(qp + 48 * CATT);

    for (int ib = 0; ib < 2048; ib += 64) {
        bf16x8 qn0, qn1, qn2, qn3;
        const bool more = (ib + 64) < 2048;
        if (more) {
            const unsigned short* q2 = qp + (size_t)(ib + 64) * CATT;
            qn0 = *reinterpret_cast<const bf16x8*>(q2);
            qn1 = *reinterpret_cast<const bf16x8*>(q2 + 16 * CATT);
            qn2 = *reinterpret_cast<const bf16x8*>(q2 + 32 * CATT);
            qn3 = *reinterpret_cast<const bf16x8*>(q2 + 48 * CATT);
        }
        f32x4 d;
        d = __builtin_amdgcn_mfma_f32_16x16x32_bf16(kfrag, qc0, zero, 0, 0, 0);
        s0 += __builtin_amdgcn_exp2f(d[0]); s1 += __builtin_amdgcn_exp2f(d[1]);
        s2 += __builtin_amdgcn_exp2f(d[2]); s3 += __builtin_amdgcn_exp2f(d[3]);
        d = __builtin_amdgcn_mfma_f32_16x16x32_bf16(kfrag, qc1, zero, 0, 0, 0);
        s0 += __builtin_amdgcn_exp2f(d[0]); s1 += __builtin_amdgcn_exp2f(d[1]);
        s2 += __builtin_amdgcn_exp2f(d[2]); s3 += __builtin_amdgcn_exp2f(d[3]);
        d = __builtin_amdgcn_mfma_f32_16x16x32_bf16(kfrag, qc2, zero, 0, 0, 0);
        s0 += __builtin_amdgcn_exp2f(d[0]); s1 += __builtin_amdgcn_exp2f(d[1]);
        s2 += __builtin_amdgcn_exp2f(d[2]); s3 += __builtin_amdgcn_exp2f(d[3]);
        d = __builtin_amdgcn_mfma_f32_16x16x32_bf16(kfrag, qc3, zero, 0, 0, 0);
        s0 += __builtin_amdgcn_exp2f(d[0]); s1 += __builtin_amdgcn_exp2f(d[1]);
        s2 += __builtin_amdgcn_exp2f(d[2]); s3 += __builtin_amdgcn_exp2f(d[3]);
        if (more) { qc0 = qn0; qc1 = qn1; qc2 = qn2; qc3 = qn3; }
    }
    #pragma unroll
    for (int m = 1; m < 16; m <<= 1) {
        s0 += __shfl_xor(s0, m); s1 += __shfl_xor(s1, m);
        s2 += __shfl_xor(s2, m); s3 += __shfl_xor(s3, m);
    }
    if (lr == 0) {
        sred[w][(lg << 2) + 0] = s0;
        sred[w][(lg << 2) + 1] = s1;
        sred[w][(lg << 2) + 2] = s2;
        sred[w][(lg << 2) + 3] = s3;
    }
    __syncthreads();
    if (t < 32) {
        const int j16 = t & 15, js = t >> 4;
        const float s = sred[js][j16] + sred[js + 2][j16];
        rs[(size_t)b * NPIX + jblk + t] = 1.0f / s;
    }
}

// ---------------------------------------------------------------------------
// K3: fused E->exp2->PV (R7 proven structure + rs folded into P).
// CHANGE vs R12: rs float4 is DISTANCE-1 REGISTER-PREFETCHED (issued after
// the gl_lds staging ops, consumed next iteration after the barrier) so its
// mid-iteration wait no longer forces the staging prefetches to drain
// (vmcnt is FIFO — R12's +8us regression).
// ---------------------------------------------------------------------------
__global__ __launch_bounds__(256, 2)
void out_kernel(const unsigned short* __restrict__ qt,
                const unsigned short* __restrict__ kt,
                const unsigned short* __restrict__ vt,
                const float* __restrict__ rs,
                const float* __restrict__ x, float* __restrict__ out)
{
    __shared__ unsigned short sV[3][128 * 64];  // [slot][c(128) x j(64)], 128B rows, piece^=(c&7)
    __shared__ unsigned short sK[2][64 * 32];   // [slot][j(64) x a(32)], 64B rows, piece^=(j&3)
    __shared__ unsigned short sPl[2][64 * 64];  // [i][j] bf16, 128B rows, piece^=(i&7)
    const int n = blockIdx.x;
    const int b = n & 3;
    const int rest = n >> 2;
    const int ch = rest & 1;
    const int it = rest >> 1;
    const int iblk = it * 64;
    const int cblk = ch * 128;
    const int t = threadIdx.x, w = t >> 6, l = t & 63, lr = l & 15, lg = l >> 4;
    const unsigned short* qb = qt + (size_t)b * NPIX * CATT;
    const unsigned short* kb = kt + (size_t)b * NPIX * CATT;
    const unsigned short* vb = vt + (size_t)b * CIN * NPIX;
    const float* rsb = rs + (size_t)b * NPIX;
    const f32x4 zero = {0.f, 0.f, 0.f, 0.f};

    // Q fragments (hoisted, registers)
    bf16x8 qfrag[4];
    #pragma unroll
    for (int nt = 0; nt < 4; ++nt)
        qfrag[nt] = *reinterpret_cast<const bf16x8*>(
            &qb[(size_t)(iblk + 16 * nt + lr) * CATT + lg * 8]);

    // ---- staging source pointers (per-lane, pre-swizzled)
    const unsigned short* vsrcq[4];
    #pragma unroll
    for (int q = 0; q < 4; ++q) {
        const int r = (4 * w + q) * 8 + (l >> 3);
        const int p = l & 7;
        vsrcq[q] = vb + (size_t)(cblk + r) * NPIX + ((p ^ (r & 7)) * 8);
    }
    const int rk = w * 16 + (l >> 2);
    const unsigned short* ksrc0 = kb + (size_t)rk * CATT + (((l & 3) ^ (rk & 3)) * 8);

    // ---- read-side byte offsets (hoisted)
    const int krow = 16 * w + lr;
    const int kbyte = krow * 64 + ((lg * 16) ^ ((krow & 3) << 4));
    const int cl0 = 32 * w + lr;
    const int cl1 = cl0 + 16;
    int vbyte[2][2];
    #pragma unroll
    for (int kk = 0; kk < 2; ++kk) {
        vbyte[0][kk] = cl0 * 128 + ((kk * 64 + lg * 16) ^ ((cl0 & 7) << 4));
        vbyte[1][kk] = cl1 * 128 + ((kk * 64 + lg * 16) ^ ((cl1 & 7) << 4));
    }
    const int swz = (lr & 7) << 4;
    const int wb0 = lr * 128 + (((16 * w + 4 * lg) * 2) ^ swz);
    const int rb_col0 = (16 * lg) ^ swz;
    const int rb_col1 = (64 + 16 * lg) ^ swz;

    f32x4 acc[2][4] = {};

    // ---- prologue: stage tile 0 (V:0, K:0); rs(0) into regs
    #pragma unroll
    for (int q = 0; q < 4; ++q) gl_lds16(vsrcq[q], &sV[0][(4 * w + q) * 512]);
    gl_lds16(ksrc0, &sK[0][w * 512]);
    const int rsoff = 16 * w + (lg << 2);
    float4 r4 = *reinterpret_cast<const float4*>(&rsb[rsoff]);
    __syncthreads();

    int vs_cur = 0;
    for (int jb = 0; jb < 64; ++jb) {
        const int vs_next = (vs_cur == 2) ? 0 : vs_cur + 1;
        const int vs_prev = (vs_cur == 0) ? 2 : vs_cur - 1;
        float4 r4n;
        if (jb < 63) {
            const int jn = (jb + 1) * 64;
            #pragma unroll
            for (int q = 0; q < 4; ++q)
                gl_lds16(vsrcq[q] + jn, &sV[vs_next][(4 * w + q) * 512]);
            gl_lds16(ksrc0 + (size_t)jn * CATT, &sK[(jb + 1) & 1][w * 512]);
            // rs(jb+1) prefetch — issued AFTER the staging ops, consumed next
            // iter (post-barrier): no mid-iteration vmcnt drain of staging.
            r4n = *reinterpret_cast<const float4*>(&rsb[jn + rsoff]);
        }
        // ---- E(jb): K from LDS, P~ = exp2(e) * rs[j] -> sPl[jb&1]
        {
            const char* skp = reinterpret_cast<const char*>(&sK[jb & 1][0]);
            const bf16x8 kf = *reinterpret_cast<const bf16x8*>(skp + kbyte);
            char* spw = reinterpret_cast<char*>(&sPl[jb & 1][0]);
            #pragma unroll
            for (int nt = 0; nt < 4; ++nt) {
                const f32x4 e = __builtin_amdgcn_mfma_f32_16x16x32_bf16(kf, qfrag[nt], zero, 0, 0, 0);
                const float p0 = __builtin_amdgcn_exp2f(e[0]) * r4.x;
                const float p1 = __builtin_amdgcn_exp2f(e[1]) * r4.y;
                const float p2 = __builtin_amdgcn_exp2f(e[2]) * r4.z;
                const float p3 = __builtin_amdgcn_exp2f(e[3]) * r4.w;
                unsigned w0, w1;
                asm("v_cvt_pk_bf16_f32 %0, %1, %2" : "=v"(w0) : "v"(p0), "v"(p1));
                asm("v_cvt_pk_bf16_f32 %0, %1, %2" : "=v"(w1) : "v"(p2), "v"(p3));
                *reinterpret_cast<uint2*>(spw + wb0 + nt * 2048) = make_uint2(w0, w1);
            }
        }
        // ---- PV(jb-1): P from sPl[(jb-1)&1], V from sV[vs_prev]
        if (jb > 0) {
            const char* spr = reinterpret_cast<const char*>(&sPl[(jb - 1) & 1][0]);
            const char* svp = reinterpret_cast<const char*>(&sV[vs_prev][0]);
            #pragma unroll
            for (int kk = 0; kk < 2; ++kk) {
                const int rbc = (kk == 0) ? rb_col0 : rb_col1;
                bf16x8 pf[4];
                #pragma unroll
                for (int nt = 0; nt < 4; ++nt)
                    pf[nt] = *reinterpret_cast<const bf16x8*>(spr + lr * 128 + nt * 2048 + rbc);
                const bf16x8 v0 = *reinterpret_cast<const bf16x8*>(svp + vbyte[0][kk]);
                const bf16x8 v1 = *reinterpret_cast<const bf16x8*>(svp + vbyte[1][kk]);
                __builtin_amdgcn_s_setprio(1);
                #pragma unroll
                for (int nt = 0; nt < 4; ++nt) {
                    acc[0][nt] = __builtin_amdgcn_mfma_f32_16x16x32_bf16(v0, pf[nt], acc[0][nt], 0, 0, 0);
                    acc[1][nt] = __builtin_amdgcn_mfma_f32_16x16x32_bf16(v1, pf[nt], acc[1][nt], 0, 0, 0);
                }
                __builtin_amdgcn_s_setprio(0);
            }
        }
        __syncthreads();   // drains vmcnt (staged tile ready) + orders LDS
        vs_cur = vs_next;
        if (jb < 63) r4 = r4n;
    }
    // ---- epilogue: PV(63): P in sPl[1], V in vs_prev of current
    {
        const int vs_prev = (vs_cur == 0) ? 2 : vs_cur - 1;
        const char* spr = reinterpret_cast<const char*>(&sPl[1][0]);
        const char* svp = reinterpret_cast<const char*>(&sV[vs_prev][0]);
        #pragma unroll
        for (int kk = 0; kk < 2; ++kk) {
            const int rbc = (kk == 0) ? rb_col0 : rb_col1;
            bf16x8 pf[4];
            #pragma unroll
            for (int nt = 0; nt < 4; ++nt)
                pf[nt] = *reinterpret_cast<const bf16x8*>(spr + lr * 128 + nt * 2048 + rbc);
            const bf16x8 v0 = *reinterpret_cast<const bf16x8*>(svp + vbyte[0][kk]);
            const bf16x8 v1 = *reinterpret_cast<const bf16x8*>(svp + vbyte[1][kk]);
            #pragma unroll
            for (int nt = 0; nt < 4; ++nt) {
                acc[0][nt] = __builtin_amdgcn_mfma_f32_16x16x32_bf16(v0, pf[nt], acc[0][nt], 0, 0, 0);
                acc[1][nt] = __builtin_amdgcn_mfma_f32_16x16x32_bf16(v1, pf[nt], acc[1][nt], 0, 0, 0);
            }
        }
    }

    const float* xb = x + (size_t)b * CIN * NPIX;
    float* ob = out + (size_t)b * CIN * NPIX;
    #pragma unroll
    for (int mt = 0; mt < 2; ++mt)
        #pragma unroll
        for (int nt = 0; nt < 4; ++nt)
            #pragma unroll
            for (int r = 0; r < 4; ++r) {
                const int c = cblk + 32 * w + 16 * mt + (lg << 2) + r;
                const size_t idx = (size_t)c * NPIX + iblk + 16 * nt + lr;
                ob[idx] = acc[mt][nt][r] + xb[idx];
            }
}

// ---------------------------------------------------------------------------
extern "C" void kernel_launch(void* const* d_in, const int* in_sizes, int n_in,
                              void* d_out, int out_size, void* d_ws, size_t ws_size,
                              hipStream_t stream)
{
    const float* x     = (const float*)d_in[0];
    const float* Wq    = (const float*)d_in[1];
    const float* bq    = (const float*)d_in[2];
    const float* Wk    = (const float*)d_in[3];
    const float* bk    = (const float*)d_in[4];
    const float* Wv    = (const float*)d_in[5];
    const float* bv    = (const float*)d_in[6];
    const float* gamma = (const float*)d_in[7];
    float* out = (float*)d_out;

    unsigned short* xT = (unsigned short*)d_ws;
    unsigned short* qt = xT + (size_t)NBATCH * NPIX * CIN;
    unsigned short* kt = qt + (size_t)NBATCH * NPIX * CATT;
    unsigned short* vt = kt + (size_t)NBATCH * NPIX * CATT;
    float* rsw = (float*)(vt + (size_t)NBATCH * CIN * NPIX);

    transpose_kernel<<<dim3(NPIX / 64, CIN / 64, NBATCH), 256, 0, stream>>>(x, xT);
    proj_fused_kernel<<<dim3(NPIX / 32, NBATCH), 256, 0, stream>>>(
        Wq, bq, Wk, bk, Wv, bv, gamma, xT, qt, kt, vt);
    stats_kernel<<<dim3((NPIX / 32) * NBATCH), 256, 0, stream>>>(qt, kt, rsw);
    out_kernel<<<dim3((NPIX / 64) * 2 * NBATCH), 256, 0, stream>>>(qt, kt, vt, rsw, x, out);
}

// Round 14
// 128.606 us; speedup vs baseline: 1.0422x; 1.0422x over previous
//
#include <hip/hip_runtime.h>

#define NBATCH 4
#define CIN 256
#define CATT 32
#define NPIX 4096

static constexpr float LOG2E_F = 1.4426950408889634f;

typedef __attribute__((ext_vector_type(8))) short bf16x8;
typedef __attribute__((ext_vector_type(4))) float f32x4;

__device__ __forceinline__ unsigned short f2bf_rne(float f) {
    unsigned u = __builtin_bit_cast(unsigned, f);
    return (unsigned short)((u + 0x7fffu + ((u >> 16) & 1u)) >> 16);
}
__device__ __forceinline__ float bf2f(unsigned short h) {
    unsigned u = (unsigned)h << 16;
    return __builtin_bit_cast(float, u);
}
__device__ __forceinline__ void split8(const float* p, bf16x8& hi, bf16x8& lo) {
    const float4 a = *reinterpret_cast<const float4*>(p);
    const float4 b = *reinterpret_cast<const float4*>(p + 4);
    const float f[8] = {a.x, a.y, a.z, a.w, b.x, b.y, b.z, b.w};
    #pragma unroll
    for (int e = 0; e < 8; ++e) {
        const unsigned short h = f2bf_rne(f[e]);
        hi[e] = (short)h;
        lo[e] = (short)f2bf_rne(f[e] - bf2f(h));
    }
}
__device__ __forceinline__ bf16x8 cvt8(const float* p) {
    const float4 a = *reinterpret_cast<const float4*>(p);
    const float4 b = *reinterpret_cast<const float4*>(p + 4);
    const float f[8] = {a.x, a.y, a.z, a.w, b.x, b.y, b.z, b.w};
    bf16x8 r;
    #pragma unroll
    for (int e = 0; e < 8; ++e) r[e] = (short)f2bf_rne(f[e]);
    return r;
}
// async global -> LDS, 16B per lane (dest = uniform base + lane*16)
__device__ __forceinline__ void gl_lds16(const unsigned short* g, unsigned short* l) {
    __builtin_amdgcn_global_load_lds(
        (const __attribute__((address_space(1))) unsigned int*)g,
        (__attribute__((address_space(3))) unsigned int*)l, 16, 0, 0);
}

// ---------------------------------------------------------------------------
// K0: x[b][c][n] f32 -> xT[b][n][256] bf16  (proven, unchanged)
// ---------------------------------------------------------------------------
__global__ __launch_bounds__(256, 2)
void transpose_kernel(const float* __restrict__ x, unsigned short* __restrict__ xT)
{
    __shared__ unsigned short sT[64][68];
    const int t = threadIdx.x;
    const int nblk = blockIdx.x * 64;
    const int cblk = blockIdx.y * 64;
    const int b = blockIdx.z;
    const float* xb = x + ((size_t)b * CIN + cblk) * NPIX + nblk;
    const int lc = t >> 2, ln = (t & 3) << 4;
    #pragma unroll
    for (int u = 0; u < 4; ++u) {
        const float4 v = *reinterpret_cast<const float4*>(&xb[(size_t)lc * NPIX + ln + 4 * u]);
        sT[ln + 4 * u + 0][lc] = f2bf_rne(v.x);
        sT[ln + 4 * u + 1][lc] = f2bf_rne(v.y);
        sT[ln + 4 * u + 2][lc] = f2bf_rne(v.z);
        sT[ln + 4 * u + 3][lc] = f2bf_rne(v.w);
    }
    __syncthreads();
    const int rn = t >> 2, cs = (t & 3) << 4;
    const uint2 d0 = *reinterpret_cast<const uint2*>(&sT[rn][cs + 0]);
    const uint2 d1 = *reinterpret_cast<const uint2*>(&sT[rn][cs + 4]);
    const uint2 d2 = *reinterpret_cast<const uint2*>(&sT[rn][cs + 8]);
    const uint2 d3 = *reinterpret_cast<const uint2*>(&sT[rn][cs + 12]);
    unsigned short* dst = xT + ((size_t)b * NPIX + nblk + rn) * CIN + cblk + cs;
    *reinterpret_cast<uint4*>(dst)     = make_uint4(d0.x, d0.y, d1.x, d1.y);
    *reinterpret_cast<uint4*>(dst + 8) = make_uint4(d2.x, d2.y, d3.x, d3.y);
}

// ---------------------------------------------------------------------------
// K1 (FUSED): q/k/v projection in one kernel (proven in R12).
//  - v part: proj_v body verbatim (all 4 waves), epilogue applies gamma only
//    (rs applied later by stats_kernel's in-place vt scale).
//  - q/k part: proj_qk body verbatim on waves 0,1 (nq = n0 + 16w).
// grid (NPIX/32, NBATCH), block 256.
// ---------------------------------------------------------------------------
__global__ __launch_bounds__(256, 2)
void proj_fused_kernel(const float* __restrict__ Wq, const float* __restrict__ bq,
                       const float* __restrict__ Wk, const float* __restrict__ bk,
                       const float* __restrict__ Wv, const float* __restrict__ bv,
                       const float* __restrict__ gamma,
                       const unsigned short* __restrict__ xT,
                       unsigned short* __restrict__ qt, unsigned short* __restrict__ kt,
                       unsigned short* __restrict__ vt)
{
    const int t = threadIdx.x, w = t >> 6, l = t & 63, lr = l & 15, lg = l >> 4;
    const int b = blockIdx.y;
    const int n0 = blockIdx.x * 32;

    // ---- q/k part (waves 0,1): proj_qk body verbatim at nq = n0 + 16w
    if (w < 2) {
        const int nq = n0 + 16 * w;
        const unsigned short* xrow = xT + ((size_t)b * NPIX + nq + lr) * CIN + lg * 8;
        f32x4 aq[2] = {{0.f,0.f,0.f,0.f},{0.f,0.f,0.f,0.f}};
        f32x4 ak2[2] = {{0.f,0.f,0.f,0.f},{0.f,0.f,0.f,0.f}};
        #pragma unroll
        for (int ks = 0; ks < 8; ++ks) {
            const int ko = ks * 32 + lg * 8;
            const bf16x8 bx = *reinterpret_cast<const bf16x8*>(xrow + ks * 32);
            #pragma unroll
            for (int mt = 0; mt < 2; ++mt) {
                bf16x8 wh, wl;
                split8(&Wq[(size_t)(mt * 16 + lr) * CIN + ko], wh, wl);
                aq[mt] = __builtin_amdgcn_mfma_f32_16x16x32_bf16(wh, bx, aq[mt], 0, 0, 0);
                aq[mt] = __builtin_amdgcn_mfma_f32_16x16x32_bf16(wl, bx, aq[mt], 0, 0, 0);
                split8(&Wk[(size_t)(mt * 16 + lr) * CIN + ko], wh, wl);
                ak2[mt] = __builtin_amdgcn_mfma_f32_16x16x32_bf16(wh, bx, ak2[mt], 0, 0, 0);
                ak2[mt] = __builtin_amdgcn_mfma_f32_16x16x32_bf16(wl, bx, ak2[mt], 0, 0, 0);
            }
        }
        #pragma unroll
        for (int mt = 0; mt < 2; ++mt) {
            const float4 b4q = *reinterpret_cast<const float4*>(&bq[16 * mt + (lg << 2)]);
            const float4 b4k = *reinterpret_cast<const float4*>(&bk[16 * mt + (lg << 2)]);
            ushort4 uq, uk;
            uq.x = f2bf_rne(LOG2E_F * (aq[mt][0] + b4q.x));
            uq.y = f2bf_rne(LOG2E_F * (aq[mt][1] + b4q.y));
            uq.z = f2bf_rne(LOG2E_F * (aq[mt][2] + b4q.z));
            uq.w = f2bf_rne(LOG2E_F * (aq[mt][3] + b4q.w));
            uk.x = f2bf_rne(ak2[mt][0] + b4k.x);
            uk.y = f2bf_rne(ak2[mt][1] + b4k.y);
            uk.z = f2bf_rne(ak2[mt][2] + b4k.z);
            uk.w = f2bf_rne(ak2[mt][3] + b4k.w);
            const size_t base = ((size_t)b * NPIX + nq + lr) * CATT + 16 * mt + (lg << 2);
            *reinterpret_cast<ushort4*>(&qt[base]) = uq;
            *reinterpret_cast<ushort4*>(&kt[base]) = uk;
        }
    }

    // ---- v part (all waves): proj_v body verbatim, epilogue gamma only
    const int cb = 64 * w;
    const unsigned short* xa = xT + ((size_t)b * NPIX + n0) * CIN;
    f32x4 acc[2][4] = {};
    #pragma unroll
    for (int ks = 0; ks < 8; ++ks) {
        const int ko = ks * 32 + lg * 8;
        bf16x8 af[2];
        #pragma unroll
        for (int mt = 0; mt < 2; ++mt)
            af[mt] = *reinterpret_cast<const bf16x8*>(&xa[(size_t)(16 * mt + lr) * CIN + ko]);
        #pragma unroll
        for (int ct = 0; ct < 4; ++ct) {
            const bf16x8 wf = cvt8(&Wv[(size_t)(cb + 16 * ct + lr) * CIN + ko]);
            #pragma unroll
            for (int mt = 0; mt < 2; ++mt)
                acc[mt][ct] = __builtin_amdgcn_mfma_f32_16x16x32_bf16(af[mt], wf, acc[mt][ct], 0, 0, 0);
        }
    }
    const float gv = gamma[0];
    #pragma unroll
    for (int mt = 0; mt < 2; ++mt) {
        const int nr = n0 + 16 * mt + (lg << 2);
        #pragma unroll
        for (int ct = 0; ct < 4; ++ct) {
            const int c = cb + 16 * ct + lr;
            const float bb = bv[c];
            ushort4 u;
            u.x = f2bf_rne(gv * (acc[mt][ct][0] + bb));
            u.y = f2bf_rne(gv * (acc[mt][ct][1] + bb));
            u.z = f2bf_rne(gv * (acc[mt][ct][2] + bb));
            u.w = f2bf_rne(gv * (acc[mt][ct][3] + bb));
            *reinterpret_cast<ushort4*>(&vt[((size_t)b * CIN + c) * NPIX + nr]) = u;
        }
    }
}

// ---------------------------------------------------------------------------
// K2: stats via MFMA (proven body) + NEW epilogue: scale vt in place.
// Each block owns (b, 32-j tile) — exactly the vt columns its rs covers.
// srs broadcast via LDS; 256 threads RMW vt[b][c=t][jblk..jblk+32) (64 B/row,
// 16 KB/block, 16.8 MB chip-wide). rs never goes to global memory.
// grid (NPIX/32)*NBATCH, block 256.
// ---------------------------------------------------------------------------
__global__ __launch_bounds__(256, 2)
void stats_kernel(const unsigned short* __restrict__ qt,
                  const unsigned short* __restrict__ kt,
                  unsigned short* __restrict__ vt)
{
    __shared__ float sred[4][16];
    __shared__ float srs[32];
    const int n = blockIdx.x;
    const int b = n & 3;
    const int jblk = (n >> 2) * 32;
    const int t = threadIdx.x, w = t >> 6, l = t & 63, lr = l & 15, lg = l >> 4;
    const int jsl = w & 1;
    const int ih = w >> 1;
    const unsigned short* qb = qt + (size_t)b * NPIX * CATT;
    const unsigned short* kb = kt + (size_t)b * NPIX * CATT;

    const bf16x8 kfrag = *reinterpret_cast<const bf16x8*>(
        &kb[(size_t)(jblk + 16 * jsl + lr) * CATT + lg * 8]);
    const f32x4 zero = {0.f, 0.f, 0.f, 0.f};
    const unsigned short* qp = qb + (size_t)(ih * 2048 + lr) * CATT + lg * 8;

    float s0 = 0.f, s1 = 0.f, s2 = 0.f, s3 = 0.f;
    bf16x8 qc0 = *reinterpret_cast<const bf16x8*>(qp);
    bf16x8 qc1 = *reinterpret_cast<const bf16x8*>(qp + 16 * CATT);
    bf16x8 qc2 = *reinterpret_cast<const bf16x8*>(qp + 32 * CATT);
    bf16x8 qc3 = *reinterpret_cast<const bf16x8*>(qp + 48 * CATT);

    for (int ib = 0; ib < 2048; ib += 64) {
        bf16x8 qn0, qn1, qn2, qn3;
        const bool more = (ib + 64) < 2048;
        if (more) {
            const unsigned short* q2 = qp + (size_t)(ib + 64) * CATT;
            qn0 = *reinterpret_cast<const bf16x8*>(q2);
            qn1 = *reinterpret_cast<const bf16x8*>(q2 + 16 * CATT);
            qn2 = *reinterpret_cast<const bf16x8*>(q2 + 32 * CATT);
            qn3 = *reinterpret_cast<const bf16x8*>(q2 + 48 * CATT);
        }
        f32x4 d;
        d = __builtin_amdgcn_mfma_f32_16x16x32_bf16(kfrag, qc0, zero, 0, 0, 0);
        s0 += __builtin_amdgcn_exp2f(d[0]); s1 += __builtin_amdgcn_exp2f(d[1]);
        s2 += __builtin_amdgcn_exp2f(d[2]); s3 += __builtin_amdgcn_exp2f(d[3]);
        d = __builtin_amdgcn_mfma_f32_16x16x32_bf16(kfrag, qc1, zero, 0, 0, 0);
        s0 += __builtin_amdgcn_exp2f(d[0]); s1 += __builtin_amdgcn_exp2f(d[1]);
        s2 += __builtin_amdgcn_exp2f(d[2]); s3 += __builtin_amdgcn_exp2f(d[3]);
        d = __builtin_amdgcn_mfma_f32_16x16x32_bf16(kfrag, qc2, zero, 0, 0, 0);
        s0 += __builtin_amdgcn_exp2f(d[0]); s1 += __builtin_amdgcn_exp2f(d[1]);
        s2 += __builtin_amdgcn_exp2f(d[2]); s3 += __builtin_amdgcn_exp2f(d[3]);
        d = __builtin_amdgcn_mfma_f32_16x16x32_bf16(kfrag, qc3, zero, 0, 0, 0);
        s0 += __builtin_amdgcn_exp2f(d[0]); s1 += __builtin_amdgcn_exp2f(d[1]);
        s2 += __builtin_amdgcn_exp2f(d[2]); s3 += __builtin_amdgcn_exp2f(d[3]);
        if (more) { qc0 = qn0; qc1 = qn1; qc2 = qn2; qc3 = qn3; }
    }
    #pragma unroll
    for (int m = 1; m < 16; m <<= 1) {
        s0 += __shfl_xor(s0, m); s1 += __shfl_xor(s1, m);
        s2 += __shfl_xor(s2, m); s3 += __shfl_xor(s3, m);
    }
    if (lr == 0) {
        sred[w][(lg << 2) + 0] = s0;
        sred[w][(lg << 2) + 1] = s1;
        sred[w][(lg << 2) + 2] = s2;
        sred[w][(lg << 2) + 3] = s3;
    }
    __syncthreads();
    if (t < 32) {
        const int j16 = t & 15, js = t >> 4;
        const float s = sred[js][j16] + sred[js + 2][j16];
        srs[t] = 1.0f / s;
    }
    __syncthreads();
    // ---- NEW: scale vt[b][c=t][jblk..jblk+32) in place by srs[]
    unsigned short* vp = vt + ((size_t)b * CIN + t) * NPIX + jblk;
    #pragma unroll
    for (int u = 0; u < 4; ++u) {
        bf16x8 v = *reinterpret_cast<const bf16x8*>(vp + 8 * u);
        bf16x8 r;
        #pragma unroll
        for (int e = 0; e < 8; ++e)
            r[e] = (short)f2bf_rne(bf2f((unsigned short)v[e]) * srs[8 * u + e]);
        *reinterpret_cast<bf16x8*>(vp + 8 * u) = r;
    }
}

// ---------------------------------------------------------------------------
// K3: fused E->exp2->PV with LDS-staged K/V (R11 VERBATIM — the proven
// 72us form; vt already carries rs*gamma).
// ---------------------------------------------------------------------------
__global__ __launch_bounds__(256, 2)
void out_kernel(const unsigned short* __restrict__ qt,
                const unsigned short* __restrict__ kt,
                const unsigned short* __restrict__ vt,
                const float* __restrict__ x, float* __restrict__ out)
{
    __shared__ unsigned short sV[3][128 * 64];  // [slot][c(128) x j(64)], 128B rows, piece^=(c&7)
    __shared__ unsigned short sK[2][64 * 32];   // [slot][j(64) x a(32)], 64B rows, piece^=(j&3)
    __shared__ unsigned short sPl[2][64 * 64];  // [i][j] bf16, 128B rows, piece^=(i&7)
    const int n = blockIdx.x;
    const int b = n & 3;
    const int rest = n >> 2;
    const int ch = rest & 1;
    const int it = rest >> 1;
    const int iblk = it * 64;
    const int cblk = ch * 128;
    const int t = threadIdx.x, w = t >> 6, l = t & 63, lr = l & 15, lg = l >> 4;
    const unsigned short* qb = qt + (size_t)b * NPIX * CATT;
    const unsigned short* kb = kt + (size_t)b * NPIX * CATT;
    const unsigned short* vb = vt + (size_t)b * CIN * NPIX;
    const f32x4 zero = {0.f, 0.f, 0.f, 0.f};

    // Q fragments (hoisted, registers)
    bf16x8 qfrag[4];
    #pragma unroll
    for (int nt = 0; nt < 4; ++nt)
        qfrag[nt] = *reinterpret_cast<const bf16x8*>(
            &qb[(size_t)(iblk + 16 * nt + lr) * CATT + lg * 8]);

    // ---- staging source pointers (per-lane, pre-swizzled)
    const unsigned short* vsrcq[4];
    #pragma unroll
    for (int q = 0; q < 4; ++q) {
        const int r = (4 * w + q) * 8 + (l >> 3);
        const int p = l & 7;
        vsrcq[q] = vb + (size_t)(cblk + r) * NPIX + ((p ^ (r & 7)) * 8);
    }
    const int rk = w * 16 + (l >> 2);
    const unsigned short* ksrc0 = kb + (size_t)rk * CATT + (((l & 3) ^ (rk & 3)) * 8);

    // ---- read-side byte offsets (hoisted)
    const int krow = 16 * w + lr;
    const int kbyte = krow * 64 + ((lg * 16) ^ ((krow & 3) << 4));
    const int cl0 = 32 * w + lr;
    const int cl1 = cl0 + 16;
    int vbyte[2][2];
    #pragma unroll
    for (int kk = 0; kk < 2; ++kk) {
        vbyte[0][kk] = cl0 * 128 + ((kk * 64 + lg * 16) ^ ((cl0 & 7) << 4));
        vbyte[1][kk] = cl1 * 128 + ((kk * 64 + lg * 16) ^ ((cl1 & 7) << 4));
    }
    const int swz = (lr & 7) << 4;
    const int wb0 = lr * 128 + (((16 * w + 4 * lg) * 2) ^ swz);
    const int rb_col0 = (16 * lg) ^ swz;
    const int rb_col1 = (64 + 16 * lg) ^ swz;

    f32x4 acc[2][4] = {};

    // ---- prologue: stage tile 0 into slots (V:0, K:0)
    #pragma unroll
    for (int q = 0; q < 4; ++q) gl_lds16(vsrcq[q], &sV[0][(4 * w + q) * 512]);
    gl_lds16(ksrc0, &sK[0][w * 512]);
    __syncthreads();

    int vs_cur = 0;
    for (int jb = 0; jb < 64; ++jb) {
        const int vs_next = (vs_cur == 2) ? 0 : vs_cur + 1;
        const int vs_prev = (vs_cur == 0) ? 2 : vs_cur - 1;
        if (jb < 63) {
            const int jn = (jb + 1) * 64;
            #pragma unroll
            for (int q = 0; q < 4; ++q)
                gl_lds16(vsrcq[q] + jn, &sV[vs_next][(4 * w + q) * 512]);
            gl_lds16(ksrc0 + (size_t)jn * CATT, &sK[(jb + 1) & 1][w * 512]);
        }
        // ---- E(jb): K from LDS, write P -> sPl[jb&1]
        {
            const char* skp = reinterpret_cast<const char*>(&sK[jb & 1][0]);
            const bf16x8 kf = *reinterpret_cast<const bf16x8*>(skp + kbyte);
            char* spw = reinterpret_cast<char*>(&sPl[jb & 1][0]);
            #pragma unroll
            for (int nt = 0; nt < 4; ++nt) {
                const f32x4 e = __builtin_amdgcn_mfma_f32_16x16x32_bf16(kf, qfrag[nt], zero, 0, 0, 0);
                const float p0 = __builtin_amdgcn_exp2f(e[0]);
                const float p1 = __builtin_amdgcn_exp2f(e[1]);
                const float p2 = __builtin_amdgcn_exp2f(e[2]);
                const float p3 = __builtin_amdgcn_exp2f(e[3]);
                unsigned w0, w1;
                asm("v_cvt_pk_bf16_f32 %0, %1, %2" : "=v"(w0) : "v"(p0), "v"(p1));
                asm("v_cvt_pk_bf16_f32 %0, %1, %2" : "=v"(w1) : "v"(p2), "v"(p3));
                *reinterpret_cast<uint2*>(spw + wb0 + nt * 2048) = make_uint2(w0, w1);
            }
        }
        // ---- PV(jb-1): P from sPl[(jb-1)&1], V from sV[vs_prev]
        if (jb > 0) {
            const char* spr = reinterpret_cast<const char*>(&sPl[(jb - 1) & 1][0]);
            const char* svp = reinterpret_cast<const char*>(&sV[vs_prev][0]);
            #pragma unroll
            for (int kk = 0; kk < 2; ++kk) {
                const int rbc = (kk == 0) ? rb_col0 : rb_col1;
                bf16x8 pf[4];
                #pragma unroll
                for (int nt = 0; nt < 4; ++nt)
                    pf[nt] = *reinterpret_cast<const bf16x8*>(spr + lr * 128 + nt * 2048 + rbc);
                const bf16x8 v0 = *reinterpret_cast<const bf16x8*>(svp + vbyte[0][kk]);
                const bf16x8 v1 = *reinterpret_cast<const bf16x8*>(svp + vbyte[1][kk]);
                __builtin_amdgcn_s_setprio(1);
                #pragma unroll
                for (int nt = 0; nt < 4; ++nt) {
                    acc[0][nt] = __builtin_amdgcn_mfma_f32_16x16x32_bf16(v0, pf[nt], acc[0][nt], 0, 0, 0);
                    acc[1][nt] = __builtin_amdgcn_mfma_f32_16x16x32_bf16(v1, pf[nt], acc[1][nt], 0, 0, 0);
                }
                __builtin_amdgcn_s_setprio(0);
            }
        }
        __syncthreads();   // drains vmcnt (staged tile ready) + orders LDS
        vs_cur = vs_next;
    }
    // ---- epilogue: PV(63): P in sPl[1], V in vs_prev of current
    {
        const int vs_prev = (vs_cur == 0) ? 2 : vs_cur - 1;
        const char* spr = reinterpret_cast<const char*>(&sPl[1][0]);
        const char* svp = reinterpret_cast<const char*>(&sV[vs_prev][0]);
        #pragma unroll
        for (int kk = 0; kk < 2; ++kk) {
            const int rbc = (kk == 0) ? rb_col0 : rb_col1;
            bf16x8 pf[4];
            #pragma unroll
            for (int nt = 0; nt < 4; ++nt)
                pf[nt] = *reinterpret_cast<const bf16x8*>(spr + lr * 128 + nt * 2048 + rbc);
            const bf16x8 v0 = *reinterpret_cast<const bf16x8*>(svp + vbyte[0][kk]);
            const bf16x8 v1 = *reinterpret_cast<const bf16x8*>(svp + vbyte[1][kk]);
            #pragma unroll
            for (int nt = 0; nt < 4; ++nt) {
                acc[0][nt] = __builtin_amdgcn_mfma_f32_16x16x32_bf16(v0, pf[nt], acc[0][nt], 0, 0, 0);
                acc[1][nt] = __builtin_amdgcn_mfma_f32_16x16x32_bf16(v1, pf[nt], acc[1][nt], 0, 0, 0);
            }
        }
    }

    const float* xb = x + (size_t)b * CIN * NPIX;
    float* ob = out + (size_t)b * CIN * NPIX;
    #pragma unroll
    for (int mt = 0; mt < 2; ++mt)
        #pragma unroll
        for (int nt = 0; nt < 4; ++nt)
            #pragma unroll
            for (int r = 0; r < 4; ++r) {
                const int c = cblk + 32 * w + 16 * mt + (lg << 2) + r;
                const size_t idx = (size_t)c * NPIX + iblk + 16 * nt + lr;
                ob[idx] = acc[mt][nt][r] + xb[idx];
            }
}

// ---------------------------------------------------------------------------
extern "C" void kernel_launch(void* const* d_in, const int* in_sizes, int n_in,
                              void* d_out, int out_size, void* d_ws, size_t ws_size,
                              hipStream_t stream)
{
    const float* x     = (const float*)d_in[0];
    const float* Wq    = (const float*)d_in[1];
    const float* bq    = (const float*)d_in[2];
    const float* Wk    = (const float*)d_in[3];
    const float* bk    = (const float*)d_in[4];
    const float* Wv    = (const float*)d_in[5];
    const float* bv    = (const float*)d_in[6];
    const float* gamma = (const float*)d_in[7];
    float* out = (float*)d_out;

    unsigned short* xT = (unsigned short*)d_ws;
    unsigned short* qt = xT + (size_t)NBATCH * NPIX * CIN;
    unsigned short* kt = qt + (size_t)NBATCH * NPIX * CATT;
    unsigned short* vt = kt + (size_t)NBATCH * NPIX * CATT;

    transpose_kernel<<<dim3(NPIX / 64, CIN / 64, NBATCH), 256, 0, stream>>>(x, xT);
    proj_fused_kernel<<<dim3(NPIX / 32, NBATCH), 256, 0, stream>>>(
        Wq, bq, Wk, bk, Wv, bv, gamma, xT, qt, kt, vt);
    stats_kernel<<<dim3((NPIX / 32) * NBATCH), 256, 0, stream>>>(qt, kt, vt);
    out_kernel<<<dim3((NPIX / 64) * 2 * NBATCH), 256, 0, stream>>>(qt, kt, vt, x, out);
}